// Round 4
// baseline (185.661 us; speedup 1.0000x reference)
//
#include <hip/hip_runtime.h>
#include <stdint.h>

#define DIM 1024
#define MOE_HID 512
#define SH_HID 2048
#define NE 16
#define NT 2048
#define ROWS_CAP 6144   // 4096 assignments + 16*127 max padding

typedef unsigned short u16;
typedef __attribute__((ext_vector_type(8))) short s16x8;
typedef __attribute__((ext_vector_type(4))) float f32x4;

__device__ __forceinline__ u16 f2bf(float f){
  union { float f; unsigned v; } x; x.f = f;
  unsigned r = x.v + 0x7FFF + ((x.v >> 16) & 1);
  return (u16)(r >> 16);
}

__device__ __forceinline__ s16x8 cvt8(float4 a, float4 b){
  s16x8 r;
  r[0] = (short)f2bf(a.x); r[1] = (short)f2bf(a.y);
  r[2] = (short)f2bf(a.z); r[3] = (short)f2bf(a.w);
  r[4] = (short)f2bf(b.x); r[5] = (short)f2bf(b.y);
  r[6] = (short)f2bf(b.z); r[7] = (short)f2bf(b.w);
  return r;
}

__device__ __forceinline__ void gld16(const void* g, void* l){
  __builtin_amdgcn_global_load_lds(
      (const __attribute__((address_space(1))) void*)g,
      (__attribute__((address_space(3))) void*)l, 16, 0, 0);
}

// ---------------- fp32 -> bf16 convert (x only: 2M elements, exact grid) ----------------
__global__ void k_cvt_x(const float* __restrict__ s, u16* __restrict__ d){
  int i = (blockIdx.x * 256 + threadIdx.x) * 4;
  float4 v = *(const float4*)(s + i);
  ushort4 o;
  o.x = f2bf(v.x); o.y = f2bf(v.y); o.z = f2bf(v.z); o.w = f2bf(v.w);
  *(ushort4*)(d + i) = o;
}

// ---------------- router: fp32 logits, top-2, scores, shared-gate logit ----------------
__global__ void k_router(const float* __restrict__ x, const float* __restrict__ Wg,
                         const float* __restrict__ Wsgate1,
                         int* __restrict__ inds, float* __restrict__ scores,
                         float* __restrict__ gl){
  int lane = threadIdx.x & 63;
  int t = blockIdx.x * 4 + (threadIdx.x >> 6);
  const float4* xt = (const float4*)(x + (size_t)t * DIM);
  float4 xv[4];
#pragma unroll
  for(int j = 0; j < 4; j++) xv[j] = xt[lane + 64 * j];

  float acc[NE + 1];
#pragma unroll
  for(int e = 0; e <= NE; e++) acc[e] = 0.f;

#pragma unroll
  for(int e = 0; e < NE; e++){
    const float4* wr = (const float4*)(Wg + (size_t)e * DIM);
#pragma unroll
    for(int j = 0; j < 4; j++){
      float4 w = wr[lane + 64 * j];
      acc[e] += xv[j].x * w.x + xv[j].y * w.y + xv[j].z * w.z + xv[j].w * w.w;
    }
  }
  {
    const float4* wr = (const float4*)Wsgate1;
#pragma unroll
    for(int j = 0; j < 4; j++){
      float4 w = wr[lane + 64 * j];
      acc[NE] += xv[j].x * w.x + xv[j].y * w.y + xv[j].z * w.z + xv[j].w * w.w;
    }
  }

#pragma unroll
  for(int off = 32; off; off >>= 1)
#pragma unroll
    for(int e = 0; e <= NE; e++) acc[e] += __shfl_xor(acc[e], off, 64);

  if(lane == 0){
    int b0 = 0; float v0 = acc[0];
    for(int e = 1; e < NE; e++) if(acc[e] > v0){ v0 = acc[e]; b0 = e; }
    int b1 = (b0 == 0) ? 1 : 0; float v1 = acc[b1];
    for(int e = 0; e < NE; e++) if(e != b0 && acc[e] > v1){ v1 = acc[e]; b1 = e; }
    float s0 = 1.f / (1.f + __expf(v1 - v0));
    inds[t*2+0] = b0; inds[t*2+1] = b1;
    scores[t*2+0] = s0; scores[t*2+1] = 1.f - s0;
    gl[t] = acc[NE];
  }
}

// ---------------- assign: histogram + padded prefix + row assignment (1 block) ----------------
__global__ void k_assign(const int* __restrict__ inds, const float* __restrict__ scores,
                         int* __restrict__ counts, int* __restrict__ offs,
                         int* __restrict__ tokrow, int* __restrict__ rowinfo,
                         float* __restrict__ rowscore){
  __shared__ int cnt[NE], off_s[NE], fill[NE];
  int tid = threadIdx.x;
  if(tid < NE){ cnt[tid] = 0; fill[tid] = 0; }
  __syncthreads();
  int ea[4];
#pragma unroll
  for(int i = 0; i < 4; i++){
    int a = tid + 1024 * i;
    ea[i] = inds[a];
    atomicAdd(&cnt[ea[i]], 1);
  }
  __syncthreads();
  if(tid == 0){
    int o = 0;
    for(int e = 0; e < NE; e++){ off_s[e] = o; o += (cnt[e] + 127) & ~127; }
  }
  __syncthreads();
#pragma unroll
  for(int i = 0; i < 4; i++){
    int a = tid + 1024 * i;
    int e = ea[i];
    int row = off_s[e] + atomicAdd(&fill[e], 1);
    tokrow[a] = row;
    rowinfo[row] = a;
    rowscore[row] = scores[a];
  }
  if(tid < NE){ counts[tid] = cnt[tid]; offs[tid] = off_s[tid]; }
}

// ---------------- scatter tokens into per-expert contiguous rows ----------------
__global__ void k_scatter(const u16* __restrict__ xb, const int* __restrict__ tokrow,
                          u16* __restrict__ Xp){
  int t = blockIdx.x;
  int r0 = tokrow[t*2], r1 = tokrow[t*2+1];
  uint4 v = ((const uint4*)(xb + (size_t)t * DIM))[threadIdx.x];
  ((uint4*)(Xp + (size_t)r0 * DIM))[threadIdx.x] = v;
  ((uint4*)(Xp + (size_t)r1 * DIM))[threadIdx.x] = v;
}

// ---------------- fused gate+up SwiGLU GEMM: H = silu(A@Bg^T) * (A@Bu^T) ----------------
// A: bf16 (gld_lds). Bg,Bu: fp32, converted to bf16 during reg-staging.
// tile 128(M) x 64(N per matrix), K step 32. 4 waves (2x2).
__global__ __launch_bounds__(256, 2) void k_gateup(
    const u16* __restrict__ Abase, const float* __restrict__ Bg_base,
    const float* __restrict__ Bu_base, u16* __restrict__ Hbase,
    const int* __restrict__ counts, const int* __restrict__ offs, int shared_mode){
  __shared__ __align__(16) u16 As[128 * 32];
  __shared__ __align__(16) u16 Bgs[64 * 32];
  __shared__ __align__(16) u16 Bus[64 * 32];

  const int tid = threadIdx.x;
  const int lane = tid & 63, wid = tid >> 6;
  const int wm = wid >> 1, wn = wid & 1;
  const int mtile = blockIdx.y;
  const int n0 = blockIdx.x * 64;

  const u16 *A; const float *Bg, *Bu; u16* H; int ldh;
  if(shared_mode){
    A = Abase + (size_t)mtile * 128 * DIM;
    Bg = Bg_base; Bu = Bu_base;
    H = Hbase + (size_t)mtile * 128 * SH_HID;
    ldh = SH_HID;
  } else {
    int e = blockIdx.z;
    int M = counts[e];
    if(mtile * 128 >= M) return;
    int ro = offs[e];
    A = Abase + ((size_t)ro + (size_t)mtile * 128) * DIM;
    Bg = Bg_base + (size_t)e * MOE_HID * DIM;
    Bu = Bu_base + (size_t)e * MOE_HID * DIM;
    H = Hbase + ((size_t)ro + (size_t)mtile * 128) * MOE_HID;
    ldh = MOE_HID;
  }

  const int srow = tid >> 2;          // 0..63
  const int sk   = (tid & 3) * 8;     // k element offset
  u16* AsB1 = As  + wid * 512;
  u16* AsB2 = As  + 2048 + wid * 512;
  u16* BgW  = Bgs + srow * 32 + sk;   // this thread's ds_write slot
  u16* BuW  = Bus + srow * 32 + sk;

  f32x4 accg[4][2], accu[4][2];
#pragma unroll
  for(int m = 0; m < 4; m++)
#pragma unroll
    for(int n = 0; n < 2; n++){
      accg[m][n] = (f32x4){0.f,0.f,0.f,0.f};
      accu[m][n] = (f32x4){0.f,0.f,0.f,0.f};
    }

  const int fr = lane & 15;
  const int fk = (lane >> 4) * 8;

  for(int kt = 0; kt < DIM; kt += 32){
    gld16(A  + (size_t)srow * DIM + kt + sk, AsB1);
    gld16(A  + (size_t)(64 + srow) * DIM + kt + sk, AsB2);
    const float* gp = Bg + (size_t)(n0 + srow) * DIM + kt + sk;
    const float* up = Bu + (size_t)(n0 + srow) * DIM + kt + sk;
    float4 g0 = *(const float4*)gp, g1 = *(const float4*)(gp + 4);
    float4 u0 = *(const float4*)up, u1 = *(const float4*)(up + 4);
    *(s16x8*)BgW = cvt8(g0, g1);
    *(s16x8*)BuW = cvt8(u0, u1);
    asm volatile("s_waitcnt vmcnt(0)" ::: "memory");
    __syncthreads();

    s16x8 af[4], bgf[2], buf2[2];
#pragma unroll
    for(int m = 0; m < 4; m++)
      af[m] = *(const s16x8*)(As + (wm*64 + m*16 + fr) * 32 + fk);
#pragma unroll
    for(int n = 0; n < 2; n++){
      bgf[n]  = *(const s16x8*)(Bgs + (wn*32 + n*16 + fr) * 32 + fk);
      buf2[n] = *(const s16x8*)(Bus + (wn*32 + n*16 + fr) * 32 + fk);
    }
#pragma unroll
    for(int m = 0; m < 4; m++)
#pragma unroll
      for(int n = 0; n < 2; n++){
        accg[m][n] = __builtin_amdgcn_mfma_f32_16x16x32_bf16(af[m], bgf[n], accg[m][n], 0, 0, 0);
        accu[m][n] = __builtin_amdgcn_mfma_f32_16x16x32_bf16(af[m], buf2[n], accu[m][n], 0, 0, 0);
      }
    __syncthreads();
  }

#pragma unroll
  for(int m = 0; m < 4; m++)
#pragma unroll
    for(int n = 0; n < 2; n++)
#pragma unroll
      for(int i = 0; i < 4; i++){
        int r = wm*64 + m*16 + ((lane >> 4) << 2) + i;
        int c = n0 + wn*32 + n*16 + (lane & 15);
        float g = accg[m][n][i], u = accu[m][n][i];
        float h = (g / (1.f + __expf(-g))) * u;
        H[(size_t)r * ldh + c] = f2bf(h);
      }
}

// ---------------- down GEMM: O = A @ B^T ----------------
// A: bf16 (gld_lds). B: fp32, converted during reg-staging.
// tile 128x128, 4 waves (2x2). Expert mode: scatter score*y to slots.
// Shared mode: blockIdx.z selects K-half; writes partial to O0/O1.
__global__ __launch_bounds__(256, 2) void k_down(
    const u16* __restrict__ Abase, const float* __restrict__ Bbase,
    float* __restrict__ O0, float* __restrict__ O1,
    const int* __restrict__ counts, const int* __restrict__ offs,
    const int* __restrict__ rowinfo, const float* __restrict__ rowscore,
    int ldK, int kspan, int shared_mode){
  __shared__ __align__(16) u16 As[128 * 32];
  __shared__ __align__(16) u16 Bs[128 * 32];
  const int tid = threadIdx.x, lane = tid & 63, wid = tid >> 6;
  const int wm = wid >> 1, wn = wid & 1;
  const int mtile = blockIdx.y, n0 = blockIdx.x * 128;

  const u16 *A; const float *B; int M = NT, roff = 0, kBeg = 0;
  float* O = O0;
  if(shared_mode){
    A = Abase + (size_t)mtile * 128 * ldK;
    B = Bbase;
    kBeg = blockIdx.z * kspan;
    if(blockIdx.z) O = O1;
  } else {
    int e = blockIdx.z;
    M = counts[e];
    if(mtile * 128 >= M) return;
    roff = offs[e] + mtile * 128;
    A = Abase + (size_t)roff * ldK;
    B = Bbase + (size_t)e * DIM * ldK;
  }
  const int kEnd = kBeg + kspan;

  const int srow = tid >> 2;
  const int sk   = (tid & 3) * 8;
  u16* BsW1 = Bs + srow * 32 + sk;
  u16* BsW2 = Bs + (64 + srow) * 32 + sk;

  f32x4 acc[4][4];
#pragma unroll
  for(int m = 0; m < 4; m++)
#pragma unroll
    for(int n = 0; n < 4; n++) acc[m][n] = (f32x4){0.f,0.f,0.f,0.f};

  const int fr = lane & 15;
  const int fk = (lane >> 4) * 8;

  for(int kt = kBeg; kt < kEnd; kt += 32){
    gld16(A + (size_t)srow * ldK + kt + sk, As + wid * 512);
    gld16(A + (size_t)(64 + srow) * ldK + kt + sk, As + 2048 + wid * 512);
    const float* b1p = B + (size_t)(n0 + srow) * ldK + kt + sk;
    const float* b2p = B + (size_t)(n0 + 64 + srow) * ldK + kt + sk;
    float4 a0 = *(const float4*)b1p, a1 = *(const float4*)(b1p + 4);
    float4 c0 = *(const float4*)b2p, c1 = *(const float4*)(b2p + 4);
    *(s16x8*)BsW1 = cvt8(a0, a1);
    *(s16x8*)BsW2 = cvt8(c0, c1);
    asm volatile("s_waitcnt vmcnt(0)" ::: "memory");
    __syncthreads();

    s16x8 af[4], bf[4];
#pragma unroll
    for(int m = 0; m < 4; m++)
      af[m] = *(const s16x8*)(As + (wm*64 + m*16 + fr) * 32 + fk);
#pragma unroll
    for(int n = 0; n < 4; n++)
      bf[n] = *(const s16x8*)(Bs + (wn*64 + n*16 + fr) * 32 + fk);
#pragma unroll
    for(int m = 0; m < 4; m++)
#pragma unroll
      for(int n = 0; n < 4; n++)
        acc[m][n] = __builtin_amdgcn_mfma_f32_16x16x32_bf16(af[m], bf[n], acc[m][n], 0, 0, 0);
    __syncthreads();
  }

#pragma unroll
  for(int m = 0; m < 4; m++)
#pragma unroll
    for(int i = 0; i < 4; i++){
      int rl = wm*64 + m*16 + ((lane >> 4) << 2) + i;
      if(shared_mode){
        float* orow = O + (size_t)(mtile*128 + rl) * DIM + n0 + wn*64 + (lane & 15);
#pragma unroll
        for(int n = 0; n < 4; n++) orow[n*16] = acc[m][n][i];
      } else if(mtile*128 + rl < M){
        int ar = roff + rl;
        int slot = rowinfo[ar];
        float sc = rowscore[ar];
        float* orow = O0 + (size_t)slot * DIM + n0 + wn*64 + (lane & 15);
#pragma unroll
        for(int n = 0; n < 4; n++) orow[n*16] = sc * acc[m][n][i];
      }
    }
}

// ---------------- combine: out = yp0 + yp1 + sigmoid(gl) * (Sh0 + Sh1) ----------------
__global__ void k_combine(const float* __restrict__ yp, const float* __restrict__ Sh0,
                          const float* __restrict__ Sh1,
                          const float* __restrict__ gl, float* __restrict__ out){
  int idx = (blockIdx.x * 256 + threadIdx.x) * 4;
  int t = idx >> 10;
  int d = idx & 1023;
  float s = 1.f / (1.f + __expf(-gl[t]));
  float4 a = *(const float4*)(yp + (size_t)(t*2)   * DIM + d);
  float4 b = *(const float4*)(yp + (size_t)(t*2+1) * DIM + d);
  float4 c0 = *(const float4*)(Sh0 + idx);
  float4 c1 = *(const float4*)(Sh1 + idx);
  float4 o;
  o.x = a.x + b.x + s * (c0.x + c1.x);
  o.y = a.y + b.y + s * (c0.y + c1.y);
  o.z = a.z + b.z + s * (c0.z + c1.z);
  o.w = a.w + b.w + s * (c0.w + c1.w);
  *(float4*)(out + idx) = o;
}

extern "C" void kernel_launch(void* const* d_in, const int* in_sizes, int n_in,
                              void* d_out, int out_size, void* d_ws, size_t ws_size,
                              hipStream_t stream){
  const float* x    = (const float*)d_in[0];
  const float* Wg   = (const float*)d_in[1];
  const float* Weg  = (const float*)d_in[2];
  const float* Weu  = (const float*)d_in[3];
  const float* Wed  = (const float*)d_in[4];
  const float* Wsg  = (const float*)d_in[5];
  const float* Wsu  = (const float*)d_in[6];
  const float* Wsd  = (const float*)d_in[7];
  const float* Wg1  = (const float*)d_in[8];
  float* out = (float*)d_out;

  char* p = (char*)d_ws;
  u16* xb     = (u16*)p;  p += (size_t)NT * DIM * 2;
  u16* Hs     = (u16*)p;  p += (size_t)NT * SH_HID * 2;
  float* Sh0  = (float*)p; p += (size_t)NT * DIM * 4;
  float* Sh1  = (float*)p; p += (size_t)NT * DIM * 4;
  u16* Xp     = (u16*)p;  p += (size_t)ROWS_CAP * DIM * 2;
  u16* Hm     = (u16*)p;  p += (size_t)ROWS_CAP * MOE_HID * 2;
  float* yp   = (float*)p; p += (size_t)NT * 2 * DIM * 4;
  int* inds   = (int*)p;  p += 4096 * 4;
  float* scores = (float*)p; p += 4096 * 4;
  float* gl   = (float*)p; p += NT * 4;
  int* counts = (int*)p;  p += 64;
  int* offs   = (int*)p;  p += 64;
  int* tokrow = (int*)p;  p += 4096 * 4;
  int* rowinfo = (int*)p; p += ROWS_CAP * 4;
  float* rowscore = (float*)p; p += ROWS_CAP * 4;

  k_cvt_x<<<NT * DIM / (256 * 4), 256, 0, stream>>>(x, xb);

  k_router<<<NT/4, 256, 0, stream>>>(x, Wg, Wg1, inds, scores, gl);
  k_assign<<<1, 1024, 0, stream>>>(inds, scores, counts, offs, tokrow, rowinfo, rowscore);
  k_scatter<<<NT, 128, 0, stream>>>(xb, tokrow, Xp);

  // expert path (weights consumed as fp32, converted in-GEMM)
  k_gateup<<<dim3(8, 16, 16), 256, 0, stream>>>(Xp, Weg, Weu, Hm, counts, offs, 0);
  k_down<<<dim3(8, 16, 16), 256, 0, stream>>>(Hm, Wed, yp, yp, counts, offs,
                                              rowinfo, rowscore, MOE_HID, MOE_HID, 0);

  // shared expert path (down split over K via blockIdx.z)
  k_gateup<<<dim3(32, 16, 1), 256, 0, stream>>>(xb, Wsg, Wsu, Hs, counts, offs, 1);
  k_down<<<dim3(8, 16, 2), 256, 0, stream>>>(Hs, Wsd, Sh0, Sh1, counts, offs,
                                             rowinfo, rowscore, SH_HID, SH_HID/2, 1);

  k_combine<<<2048, 256, 0, stream>>>(yp, Sh0, Sh1, gl, out);
}

// Round 5
// 161.530 us; speedup vs baseline: 1.1494x; 1.1494x over previous
//
#include <hip/hip_runtime.h>
#include <stdint.h>

#define DIM 1024
#define MOE_HID 512
#define SH_HID 2048
#define NE 16
#define NT 2048
#define ROWS_CAP 6144   // 4096 assignments + 16*127 max padding

typedef unsigned short u16;
typedef __attribute__((ext_vector_type(8))) short s16x8;
typedef __attribute__((ext_vector_type(4))) float f32x4;

__device__ __forceinline__ u16 f2bf(float f){
  union { float f; unsigned v; } x; x.f = f;
  unsigned r = x.v + 0x7FFF + ((x.v >> 16) & 1);
  return (u16)(r >> 16);
}

// packed f32->bf16 (RNE), 2 elems/op
__device__ __forceinline__ s16x8 cvt8pk(float4 a, float4 b){
  union { s16x8 v; unsigned u[4]; } r;
  asm volatile("v_cvt_pk_bf16_f32 %0, %1, %2" : "=v"(r.u[0]) : "v"(a.x), "v"(a.y));
  asm volatile("v_cvt_pk_bf16_f32 %0, %1, %2" : "=v"(r.u[1]) : "v"(a.z), "v"(a.w));
  asm volatile("v_cvt_pk_bf16_f32 %0, %1, %2" : "=v"(r.u[2]) : "v"(b.x), "v"(b.y));
  asm volatile("v_cvt_pk_bf16_f32 %0, %1, %2" : "=v"(r.u[3]) : "v"(b.z), "v"(b.w));
  return r.v;
}

__device__ __forceinline__ void gld16(const void* g, void* l){
  __builtin_amdgcn_global_load_lds(
      (const __attribute__((address_space(1))) void*)g,
      (__attribute__((address_space(3))) void*)l, 16, 0, 0);
}

// ---------------- fp32 -> bf16 convert (x only) ----------------
__global__ void k_cvt_x(const float* __restrict__ s, u16* __restrict__ d){
  int i = (blockIdx.x * 256 + threadIdx.x) * 4;
  float4 v = *(const float4*)(s + i);
  ushort4 o;
  o.x = f2bf(v.x); o.y = f2bf(v.y); o.z = f2bf(v.z); o.w = f2bf(v.w);
  *(ushort4*)(d + i) = o;
}

// ---------------- router ----------------
__global__ void k_router(const float* __restrict__ x, const float* __restrict__ Wg,
                         const float* __restrict__ Wsgate1,
                         int* __restrict__ inds, float* __restrict__ scores,
                         float* __restrict__ gl){
  int lane = threadIdx.x & 63;
  int t = blockIdx.x * 4 + (threadIdx.x >> 6);
  const float4* xt = (const float4*)(x + (size_t)t * DIM);
  float4 xv[4];
#pragma unroll
  for(int j = 0; j < 4; j++) xv[j] = xt[lane + 64 * j];

  float acc[NE + 1];
#pragma unroll
  for(int e = 0; e <= NE; e++) acc[e] = 0.f;

#pragma unroll
  for(int e = 0; e < NE; e++){
    const float4* wr = (const float4*)(Wg + (size_t)e * DIM);
#pragma unroll
    for(int j = 0; j < 4; j++){
      float4 w = wr[lane + 64 * j];
      acc[e] += xv[j].x * w.x + xv[j].y * w.y + xv[j].z * w.z + xv[j].w * w.w;
    }
  }
  {
    const float4* wr = (const float4*)Wsgate1;
#pragma unroll
    for(int j = 0; j < 4; j++){
      float4 w = wr[lane + 64 * j];
      acc[NE] += xv[j].x * w.x + xv[j].y * w.y + xv[j].z * w.z + xv[j].w * w.w;
    }
  }

#pragma unroll
  for(int off = 32; off; off >>= 1)
#pragma unroll
    for(int e = 0; e <= NE; e++) acc[e] += __shfl_xor(acc[e], off, 64);

  if(lane == 0){
    int b0 = 0; float v0 = acc[0];
    for(int e = 1; e < NE; e++) if(acc[e] > v0){ v0 = acc[e]; b0 = e; }
    int b1 = (b0 == 0) ? 1 : 0; float v1 = acc[b1];
    for(int e = 0; e < NE; e++) if(e != b0 && acc[e] > v1){ v1 = acc[e]; b1 = e; }
    float s0 = 1.f / (1.f + __expf(v1 - v0));
    inds[t*2+0] = b0; inds[t*2+1] = b1;
    scores[t*2+0] = s0; scores[t*2+1] = 1.f - s0;
    gl[t] = acc[NE];
  }
}

// ---------------- assign: histogram + padded prefix + rows (1 block) ----------------
__global__ void k_assign(const int* __restrict__ inds, const float* __restrict__ scores,
                         int* __restrict__ counts, int* __restrict__ offs,
                         int* __restrict__ tokrow, int* __restrict__ rowinfo,
                         float* __restrict__ rowscore){
  __shared__ int cnt[NE], off_s[NE], fill[NE];
  int tid = threadIdx.x;
  if(tid < NE){ cnt[tid] = 0; fill[tid] = 0; }
  __syncthreads();
  int ea[4];
#pragma unroll
  for(int i = 0; i < 4; i++){
    int a = tid + 1024 * i;
    ea[i] = inds[a];
    atomicAdd(&cnt[ea[i]], 1);
  }
  __syncthreads();
  if(tid == 0){
    int o = 0;
    for(int e = 0; e < NE; e++){ off_s[e] = o; o += (cnt[e] + 127) & ~127; }
  }
  __syncthreads();
#pragma unroll
  for(int i = 0; i < 4; i++){
    int a = tid + 1024 * i;
    int e = ea[i];
    int row = off_s[e] + atomicAdd(&fill[e], 1);
    tokrow[a] = row;
    rowinfo[row] = a;
    rowscore[row] = scores[a];
  }
  if(tid < NE){ counts[tid] = cnt[tid]; offs[tid] = off_s[tid]; }
}

// ---------------- scatter ----------------
__global__ void k_scatter(const u16* __restrict__ xb, const int* __restrict__ tokrow,
                          u16* __restrict__ Xp){
  int t = blockIdx.x;
  int r0 = tokrow[t*2], r1 = tokrow[t*2+1];
  uint4 v = ((const uint4*)(xb + (size_t)t * DIM))[threadIdx.x];
  ((uint4*)(Xp + (size_t)r0 * DIM))[threadIdx.x] = v;
  ((uint4*)(Xp + (size_t)r1 * DIM))[threadIdx.x] = v;
}

// ================= merged gate+up SwiGLU GEMM (experts z=0..15, shared z=16) =================
// H = silu(A@Bg^T) * (A@Bu^T). Tile 128(M) x 64(N), BK=32, double-buffered,
// 1 barrier/K-step, XOR-swizzled LDS (16B unit: p ^= (row>>1)&3).
__global__ __launch_bounds__(256, 2) void k_gateup_all(
    const u16* __restrict__ Xp, const u16* __restrict__ xb,
    const float* __restrict__ Weg, const float* __restrict__ Weu,
    const float* __restrict__ Wsg, const float* __restrict__ Wsu,
    u16* __restrict__ Hm, u16* __restrict__ Hs,
    const int* __restrict__ counts, const int* __restrict__ offs){
  __shared__ __align__(16) u16 As[2][128 * 32];
  __shared__ __align__(16) u16 Bgs[2][64 * 32];
  __shared__ __align__(16) u16 Bus[2][64 * 32];

  const int z = blockIdx.z;
  const int mtile = blockIdx.y;
  const int n0 = blockIdx.x * 64;

  const u16* A; const float *Bg, *Bu; u16* H; int ldh;
  if(z == NE){
    A = xb + (size_t)mtile * 128 * DIM;
    Bg = Wsg; Bu = Wsu;
    H = Hs + (size_t)mtile * 128 * SH_HID;
    ldh = SH_HID;
  } else {
    if(n0 >= MOE_HID) return;
    int M = counts[z];
    if(mtile * 128 >= M) return;
    int ro = offs[z] + mtile * 128;
    A = Xp + (size_t)ro * DIM;
    Bg = Weg + (size_t)z * MOE_HID * DIM;
    Bu = Weu + (size_t)z * MOE_HID * DIM;
    H = Hm + (size_t)ro * MOE_HID;
    ldh = MOE_HID;
  }

  const int tid = threadIdx.x, lane = tid & 63, wid = tid >> 6;
  const int wm = wid >> 1, wn = wid & 1;
  const int srow = tid >> 2;
  const int swz8 = (((tid & 3) ^ ((tid >> 3) & 3))) * 8;   // staging col offset (elems)
  const int fr = lane & 15;
  const int fkswz = (((lane >> 4) ^ ((lane >> 1) & 3))) * 8; // frag-read col offset

  const u16* Ar0 = A + (size_t)srow * DIM + swz8;
  const u16* Ar1 = A + (size_t)(64 + srow) * DIM + swz8;
  const float* Bgr = Bg + (size_t)(n0 + srow) * DIM + (tid & 3) * 8;
  const float* Bur = Bu + (size_t)(n0 + srow) * DIM + (tid & 3) * 8;
  const int wslot = srow * 32 + swz8;

  f32x4 accg[4][2], accu[4][2];
#pragma unroll
  for(int m = 0; m < 4; m++)
#pragma unroll
    for(int n = 0; n < 2; n++){
      accg[m][n] = (f32x4){0.f,0.f,0.f,0.f};
      accu[m][n] = (f32x4){0.f,0.f,0.f,0.f};
    }

  // prologue: tile 0 in flight
  gld16(Ar0, As[0] + wid * 512);
  gld16(Ar1, As[0] + 2048 + wid * 512);
  float4 g0 = *(const float4*)Bgr,       g1 = *(const float4*)(Bgr + 4);
  float4 u0 = *(const float4*)Bur,       u1 = *(const float4*)(Bur + 4);

  int cur = 0;
  for(int t = 0; t < 32; t++){
    asm volatile("s_waitcnt vmcnt(0)" ::: "memory");   // tile t (A in LDS, B in regs) ready
    *(s16x8*)(Bgs[cur] + wslot) = cvt8pk(g0, g1);
    *(s16x8*)(Bus[cur] + wslot) = cvt8pk(u0, u1);
    __syncthreads();
    if(t < 31){
      int kn = (t + 1) * 32;
      gld16(Ar0 + kn, As[cur^1] + wid * 512);
      gld16(Ar1 + kn, As[cur^1] + 2048 + wid * 512);
      g0 = *(const float4*)(Bgr + kn); g1 = *(const float4*)(Bgr + kn + 4);
      u0 = *(const float4*)(Bur + kn); u1 = *(const float4*)(Bur + kn + 4);
    }
    s16x8 af[4], bgf[2], buf2[2];
#pragma unroll
    for(int m = 0; m < 4; m++)
      af[m] = *(const s16x8*)(As[cur] + (wm*64 + m*16 + fr) * 32 + fkswz);
#pragma unroll
    for(int n = 0; n < 2; n++){
      bgf[n]  = *(const s16x8*)(Bgs[cur] + (wn*32 + n*16 + fr) * 32 + fkswz);
      buf2[n] = *(const s16x8*)(Bus[cur] + (wn*32 + n*16 + fr) * 32 + fkswz);
    }
#pragma unroll
    for(int m = 0; m < 4; m++)
#pragma unroll
      for(int n = 0; n < 2; n++){
        accg[m][n] = __builtin_amdgcn_mfma_f32_16x16x32_bf16(af[m], bgf[n], accg[m][n], 0, 0, 0);
        accu[m][n] = __builtin_amdgcn_mfma_f32_16x16x32_bf16(af[m], buf2[n], accu[m][n], 0, 0, 0);
      }
    cur ^= 1;
  }

#pragma unroll
  for(int m = 0; m < 4; m++)
#pragma unroll
    for(int n = 0; n < 2; n++)
#pragma unroll
      for(int i = 0; i < 4; i++){
        int r = wm*64 + m*16 + ((lane >> 4) << 2) + i;
        int c = n0 + wn*32 + n*16 + (lane & 15);
        float g = accg[m][n][i], u = accu[m][n][i];
        float h = (g / (1.f + __expf(-g))) * u;
        H[(size_t)r * ldh + c] = f2bf(h);
      }
}

// ================= merged down GEMM (experts z=0..15, shared K-halves z=16,17) =================
// O = A @ B^T. Tile 128x128, BK=32, double-buffered, 1 barrier/K-step, swizzled LDS.
__global__ __launch_bounds__(256, 2) void k_down_all(
    const u16* __restrict__ Hm, const u16* __restrict__ Hs,
    const float* __restrict__ Wed, const float* __restrict__ Wsd,
    float* __restrict__ yp, float* __restrict__ Sh0, float* __restrict__ Sh1,
    const int* __restrict__ counts, const int* __restrict__ offs,
    const int* __restrict__ rowinfo, const float* __restrict__ rowscore){
  __shared__ __align__(16) u16 As[2][128 * 32];
  __shared__ __align__(16) u16 Bs[2][128 * 32];

  const int z = blockIdx.z, mtile = blockIdx.y, n0 = blockIdx.x * 128;
  const bool sh = (z >= NE);
  const u16* A; const float* B; float* O = yp;
  int lda, M = NT, roff = 0, kBeg = 0, nk;
  if(sh){
    A = Hs + (size_t)mtile * 128 * SH_HID; lda = SH_HID;
    B = Wsd; kBeg = (z - NE) * 1024; nk = 32;
    O = (z == NE) ? Sh0 : Sh1;
  } else {
    M = counts[z];
    if(mtile * 128 >= M) return;
    roff = offs[z] + mtile * 128;
    A = Hm + (size_t)roff * MOE_HID; lda = MOE_HID;
    B = Wed + (size_t)z * DIM * MOE_HID; nk = 16;
  }

  const int tid = threadIdx.x, lane = tid & 63, wid = tid >> 6;
  const int wm = wid >> 1, wn = wid & 1;
  const int srow = tid >> 2;
  const int swz8 = (((tid & 3) ^ ((tid >> 3) & 3))) * 8;
  const int fr = lane & 15;
  const int fkswz = (((lane >> 4) ^ ((lane >> 1) & 3))) * 8;

  const u16* Ar0 = A + (size_t)srow * lda + kBeg + swz8;
  const u16* Ar1 = A + (size_t)(64 + srow) * lda + kBeg + swz8;
  const float* Br0 = B + (size_t)(n0 + srow) * lda + kBeg + (tid & 3) * 8;
  const float* Br1 = B + (size_t)(n0 + 64 + srow) * lda + kBeg + (tid & 3) * 8;
  const int wslot0 = srow * 32 + swz8;
  const int wslot1 = (64 + srow) * 32 + swz8;

  f32x4 acc[4][4];
#pragma unroll
  for(int m = 0; m < 4; m++)
#pragma unroll
    for(int n = 0; n < 4; n++) acc[m][n] = (f32x4){0.f,0.f,0.f,0.f};

  gld16(Ar0, As[0] + wid * 512);
  gld16(Ar1, As[0] + 2048 + wid * 512);
  float4 b00 = *(const float4*)Br0, b01 = *(const float4*)(Br0 + 4);
  float4 b10 = *(const float4*)Br1, b11 = *(const float4*)(Br1 + 4);

  int cur = 0;
  for(int t = 0; t < nk; t++){
    asm volatile("s_waitcnt vmcnt(0)" ::: "memory");
    *(s16x8*)(Bs[cur] + wslot0) = cvt8pk(b00, b01);
    *(s16x8*)(Bs[cur] + wslot1) = cvt8pk(b10, b11);
    __syncthreads();
    if(t < nk - 1){
      int kn = (t + 1) * 32;
      gld16(Ar0 + kn, As[cur^1] + wid * 512);
      gld16(Ar1 + kn, As[cur^1] + 2048 + wid * 512);
      b00 = *(const float4*)(Br0 + kn); b01 = *(const float4*)(Br0 + kn + 4);
      b10 = *(const float4*)(Br1 + kn); b11 = *(const float4*)(Br1 + kn + 4);
    }
    s16x8 af[4], bf[4];
#pragma unroll
    for(int m = 0; m < 4; m++)
      af[m] = *(const s16x8*)(As[cur] + (wm*64 + m*16 + fr) * 32 + fkswz);
#pragma unroll
    for(int n = 0; n < 4; n++)
      bf[n] = *(const s16x8*)(Bs[cur] + (wn*64 + n*16 + fr) * 32 + fkswz);
#pragma unroll
    for(int m = 0; m < 4; m++)
#pragma unroll
      for(int n = 0; n < 4; n++)
        acc[m][n] = __builtin_amdgcn_mfma_f32_16x16x32_bf16(af[m], bf[n], acc[m][n], 0, 0, 0);
    cur ^= 1;
  }

#pragma unroll
  for(int m = 0; m < 4; m++)
#pragma unroll
    for(int i = 0; i < 4; i++){
      int rl = wm*64 + m*16 + ((lane >> 4) << 2) + i;
      if(sh){
        float* orow = O + (size_t)(mtile*128 + rl) * DIM + n0 + wn*64 + (lane & 15);
#pragma unroll
        for(int n = 0; n < 4; n++) orow[n*16] = acc[m][n][i];
      } else if(mtile*128 + rl < M){
        int ar = roff + rl;
        int slot = rowinfo[ar];
        float sc = rowscore[ar];
        float* orow = yp + (size_t)slot * DIM + n0 + wn*64 + (lane & 15);
#pragma unroll
        for(int n = 0; n < 4; n++) orow[n*16] = sc * acc[m][n][i];
      }
    }
}

// ---------------- combine ----------------
__global__ void k_combine(const float* __restrict__ yp, const float* __restrict__ Sh0,
                          const float* __restrict__ Sh1,
                          const float* __restrict__ gl, float* __restrict__ out){
  int idx = (blockIdx.x * 256 + threadIdx.x) * 4;
  int t = idx >> 10;
  float s = 1.f / (1.f + __expf(-gl[t]));
  float4 a = *(const float4*)(yp + (size_t)(t*2)   * DIM + (idx & 1023));
  float4 b = *(const float4*)(yp + (size_t)(t*2+1) * DIM + (idx & 1023));
  float4 c0 = *(const float4*)(Sh0 + idx);
  float4 c1 = *(const float4*)(Sh1 + idx);
  float4 o;
  o.x = a.x + b.x + s * (c0.x + c1.x);
  o.y = a.y + b.y + s * (c0.y + c1.y);
  o.z = a.z + b.z + s * (c0.z + c1.z);
  o.w = a.w + b.w + s * (c0.w + c1.w);
  *(float4*)(out + idx) = o;
}

extern "C" void kernel_launch(void* const* d_in, const int* in_sizes, int n_in,
                              void* d_out, int out_size, void* d_ws, size_t ws_size,
                              hipStream_t stream){
  const float* x    = (const float*)d_in[0];
  const float* Wg   = (const float*)d_in[1];
  const float* Weg  = (const float*)d_in[2];
  const float* Weu  = (const float*)d_in[3];
  const float* Wed  = (const float*)d_in[4];
  const float* Wsg  = (const float*)d_in[5];
  const float* Wsu  = (const float*)d_in[6];
  const float* Wsd  = (const float*)d_in[7];
  const float* Wg1  = (const float*)d_in[8];
  float* out = (float*)d_out;

  char* p = (char*)d_ws;
  u16* xb     = (u16*)p;  p += (size_t)NT * DIM * 2;
  u16* Hs     = (u16*)p;  p += (size_t)NT * SH_HID * 2;
  float* Sh0  = (float*)p; p += (size_t)NT * DIM * 4;
  float* Sh1  = (float*)p; p += (size_t)NT * DIM * 4;
  u16* Xp     = (u16*)p;  p += (size_t)ROWS_CAP * DIM * 2;
  u16* Hm     = (u16*)p;  p += (size_t)ROWS_CAP * MOE_HID * 2;
  float* yp   = (float*)p; p += (size_t)NT * 2 * DIM * 4;
  int* inds   = (int*)p;  p += 4096 * 4;
  float* scores = (float*)p; p += 4096 * 4;
  float* gl   = (float*)p; p += NT * 4;
  int* counts = (int*)p;  p += 64;
  int* offs   = (int*)p;  p += 64;
  int* tokrow = (int*)p;  p += 4096 * 4;
  int* rowinfo = (int*)p; p += ROWS_CAP * 4;
  float* rowscore = (float*)p; p += ROWS_CAP * 4;

  k_cvt_x<<<NT * DIM / (256 * 4), 256, 0, stream>>>(x, xb);
  k_router<<<NT/4, 256, 0, stream>>>(x, Wg, Wg1, inds, scores, gl);
  k_assign<<<1, 1024, 0, stream>>>(inds, scores, counts, offs, tokrow, rowinfo, rowscore);
  k_scatter<<<NT, 128, 0, stream>>>(xb, tokrow, Xp);

  // all gate+up GEMMs in one launch (experts z=0..15, shared z=16)
  k_gateup_all<<<dim3(32, 16, 17), 256, 0, stream>>>(Xp, xb, Weg, Weu, Wsg, Wsu,
                                                     Hm, Hs, counts, offs);
  // all down GEMMs in one launch (experts z=0..15, shared K-halves z=16,17)
  k_down_all<<<dim3(8, 16, 18), 256, 0, stream>>>(Hm, Hs, Wed, Wsd,
                                                  yp, Sh0, Sh1, counts, offs,
                                                  rowinfo, rowscore);

  k_combine<<<2048, 256, 0, stream>>>(yp, Sh0, Sh1, gl, out);
}